// Round 6
// baseline (632.930 us; speedup 1.0000x reference)
//
#include <hip/hip_runtime.h>
#include <hip/hip_bf16.h>
#include <stdint.h>

// Problem constants
#define B_   4
#define LQ_  2048
#define LKV_ 2048
#define E_   2048
#define AUG_ 1024
#define H_   16
#define DH_  128

typedef unsigned short u16;
typedef __bf16 bf16x8 __attribute__((ext_vector_type(8)));
typedef float f32x4 __attribute__((ext_vector_type(4)));
typedef float f32x16 __attribute__((ext_vector_type(16)));
typedef int i32x2 __attribute__((ext_vector_type(2)));

__device__ __forceinline__ u16 f2bf(float f) {
  union { float f; unsigned u; } v; v.f = f;
  unsigned r = v.u + 0x7fffu + ((v.u >> 16) & 1u);
  return (u16)(r >> 16);
}
__device__ __forceinline__ unsigned pk2(float a, float b) {
  return (unsigned)f2bf(a) | ((unsigned)f2bf(b) << 16);
}
// v_cvt_pk_bf16_f32: lo -> bits[15:0], hi -> bits[31:16] (no builtin on gfx950)
__device__ __forceinline__ unsigned cvtpk_bf16(float lo, float hi) {
  unsigned r;
  asm("v_cvt_pk_bf16_f32 %0, %1, %2" : "=v"(r) : "v"(lo), "v"(hi));
  return r;
}

// async global->LDS, 16B per lane. LDS dest must be wave-uniform; HW adds lane*16.
#define GLDS(gsrc, ldst)                                                        \
  __builtin_amdgcn_global_load_lds(                                             \
      (__attribute__((address_space(1))) void*)(uintptr_t)(gsrc),               \
      (__attribute__((address_space(3))) void*)(unsigned)(uintptr_t)(ldst),     \
      16, 0, 0)

// raw workgroup barrier with compiler memory-motion fences (NO vmcnt drain)
#define BARRIER()                                   \
  do {                                              \
    asm volatile("" ::: "memory");                  \
    __builtin_amdgcn_s_barrier();                   \
    asm volatile("" ::: "memory");                  \
  } while (0)

// ---------------------------------------------------------------- cast f32->bf16
__global__ __launch_bounds__(256) void cast_bf16(const float* __restrict__ in,
                                                 u16* __restrict__ out, int n8) {
  int stride = gridDim.x * blockDim.x;
  for (int i = blockIdx.x * blockDim.x + threadIdx.x; i < n8; i += stride) {
    const float4* p = (const float4*)in + (size_t)i * 2;
    float4 a = p[0], b = p[1];
    uint4 o;
    o.x = pk2(a.x, a.y); o.y = pk2(a.z, a.w);
    o.z = pk2(b.x, b.y); o.w = pk2(b.z, b.w);
    ((uint4*)out)[i] = o;
  }
}

// ------------------------------------------------- GEMM: C[M,N] = A[M,K]*W[N,K]^T + bias
// 256x256 tile, 8 waves (2M x 4N), BK=32, ring-of-3 K-tile LDS pipeline (96 KiB).
template <int OUTF32>
__global__ __launch_bounds__(512, 2) void gemm_bt2(const u16* __restrict__ A,
                                                   const u16* __restrict__ W,
                                                   const float* __restrict__ bias,
                                                   void* __restrict__ Cp,
                                                   int N, int K) {
  __shared__ __align__(16) u16 As[3][256 * 32];
  __shared__ __align__(16) u16 Bs[3][256 * 32];
  const int tid = threadIdx.x;
  const int wave = tid >> 6, lane = tid & 63;
  const int wr = wave >> 2, wc = wave & 3;          // 2 x 4 wave grid
  const int g = lane >> 4, r16 = lane & 15;
  const int m0 = blockIdx.y << 8, n0 = blockIdx.x << 8;

  size_t gA[2], gB[2];
  int ldst[2];
#pragma unroll
  for (int i = 0; i < 2; ++i) {
    int c = tid + i * 512;
    int s = c >> 6, w = c & 63;
    int wp = w ^ (((w >> 5) & 1) << 1);
    int grow = s * 16 + (wp >> 2);
    int gcol = (wp & 3) * 8;
    gA[i] = (size_t)(m0 + grow) * K + gcol;
    gB[i] = (size_t)(n0 + grow) * K + gcol;
    ldst[i] = c * 8;  // u16 elements (16B chunks)
  }
  const int aoff = r16 * 32 + ((g * 8) ^ ((r16 & 8) ? 16 : 0));

  f32x4 acc[8][4];
#pragma unroll
  for (int m = 0; m < 8; ++m)
#pragma unroll
    for (int n = 0; n < 4; ++n) acc[m][n] = (f32x4){0.f, 0.f, 0.f, 0.f};

  const int NT = K >> 5;
#pragma unroll
  for (int i = 0; i < 2; ++i) GLDS(A + gA[i], &As[0][ldst[i]]);
#pragma unroll
  for (int i = 0; i < 2; ++i) GLDS(W + gB[i], &Bs[0][ldst[i]]);
#pragma unroll
  for (int i = 0; i < 2; ++i) GLDS(A + gA[i] + 32, &As[1][ldst[i]]);
#pragma unroll
  for (int i = 0; i < 2; ++i) GLDS(W + gB[i] + 32, &Bs[1][ldst[i]]);

  int cur = 0;
  for (int t = 0; t < NT; ++t) {
    if (t + 1 < NT)
      asm volatile("s_waitcnt vmcnt(4)" ::: "memory");
    else
      asm volatile("s_waitcnt vmcnt(0)" ::: "memory");
    BARRIER();

    const u16* as = As[cur];
    const u16* bs = Bs[cur];
    int nxt = cur + 2; if (nxt >= 3) nxt -= 3;

    bf16x8 bfr[4], af[4];
#pragma unroll
    for (int n = 0; n < 4; ++n)
      bfr[n] = *(const bf16x8*)&bs[wc * 2048 + n * 512 + aoff];
#pragma unroll
    for (int m = 0; m < 4; ++m)
      af[m] = *(const bf16x8*)&as[wr * 4096 + m * 512 + aoff];
    if (t + 2 < NT) {
      size_t k0 = (size_t)(t + 2) * 32;
#pragma unroll
      for (int i = 0; i < 2; ++i) GLDS(A + gA[i] + k0, &As[nxt][ldst[i]]);
    }
    BARRIER();
    __builtin_amdgcn_s_setprio(1);
#pragma unroll
    for (int m = 0; m < 4; ++m)
#pragma unroll
      for (int n = 0; n < 4; ++n)
        acc[m][n] = __builtin_amdgcn_mfma_f32_16x16x32_bf16(af[m], bfr[n], acc[m][n], 0, 0, 0);
    __builtin_amdgcn_s_setprio(0);

    bf16x8 af2[4];
#pragma unroll
    for (int m = 0; m < 4; ++m)
      af2[m] = *(const bf16x8*)&as[wr * 4096 + (m + 4) * 512 + aoff];
    if (t + 2 < NT) {
      size_t k0 = (size_t)(t + 2) * 32;
#pragma unroll
      for (int i = 0; i < 2; ++i) GLDS(W + gB[i] + k0, &Bs[nxt][ldst[i]]);
    }
    BARRIER();
    __builtin_amdgcn_s_setprio(1);
#pragma unroll
    for (int m = 0; m < 4; ++m)
#pragma unroll
      for (int n = 0; n < 4; ++n)
        acc[m + 4][n] = __builtin_amdgcn_mfma_f32_16x16x32_bf16(af2[m], bfr[n], acc[m + 4][n], 0, 0, 0);
    __builtin_amdgcn_s_setprio(0);

    cur = cur + 1; if (cur >= 3) cur -= 3;
  }

  float bv[4];
#pragma unroll
  for (int n = 0; n < 4; ++n)
    bv[n] = bias ? bias[n0 + wc * 64 + n * 16 + r16] : 0.f;
#pragma unroll
  for (int m = 0; m < 8; ++m) {
    int row = m0 + wr * 128 + m * 16 + g * 4;
#pragma unroll
    for (int n = 0; n < 4; ++n) {
      int col = n0 + wc * 64 + n * 16 + r16;
#pragma unroll
      for (int r = 0; r < 4; ++r) {
        float v = acc[m][n][r] + bv[n];
        if (OUTF32)
          ((float*)Cp)[(size_t)(row + r) * N + col] = v;
        else
          ((u16*)Cp)[(size_t)(row + r) * N + col] = f2bf(v);
      }
    }
  }
}

// ------------------------------------------------- V transpose: [B,LKV,H,DH] -> [B,H,DH,LKV]
__global__ __launch_bounds__(256) void transpose_v(const u16* __restrict__ v,
                                                   u16* __restrict__ vt) {
  __shared__ __align__(16) u16 t[64][72];
  int tid = threadIdx.x;
  int bh = blockIdx.z, b = bh >> 4, h = bh & 15;
  int kv0 = blockIdx.x << 6, d0 = blockIdx.y << 6;
  int gr = tid & 7, rw = tid >> 3;  // rw 0..31
#pragma unroll
  for (int p = 0; p < 2; ++p) {
    int row = rw + p * 32;  // kv-local
    uint4 x = *(const uint4*)&v[((size_t)(b * LKV_) + kv0 + row) * E_ + h * DH_ + d0 + gr * 8];
    *(uint4*)&t[row][gr * 8] = x;
  }
  __syncthreads();
#pragma unroll
  for (int p = 0; p < 2; ++p) {
    int d = rw + p * 32;  // d-local
    u16 tmp[8];
#pragma unroll
    for (int j = 0; j < 8; ++j) tmp[j] = t[gr * 8 + j][d];
    uint4 o;
    o.x = (unsigned)tmp[0] | ((unsigned)tmp[1] << 16);
    o.y = (unsigned)tmp[2] | ((unsigned)tmp[3] << 16);
    o.z = (unsigned)tmp[4] | ((unsigned)tmp[5] << 16);
    o.w = (unsigned)tmp[6] | ((unsigned)tmp[7] << 16);
    *(uint4*)&vt[(((size_t)(b * H_ + h)) * DH_ + d0 + d) * LKV_ + kv0 + gr * 8] = o;
  }
}

// ------------------------------------------------- flash attention (m214-style)
// Block: 256 thr (4 waves), QBLK=128 (32 q-rows/wave), KVBLK=64, 32x32x16 MFMA.
// Swapped QK^T: S^T = mfma(A=K, B=Q) -> lane owns q = lane&31; kv spread over
// 16 regs x hi-half: kv = (r&3)+8*(r>>2)+4*hi (+n*32).
// Fixed-shift softmax in-register; P -> bf16 PV A-frags via v_cvt_pk_bf16_f32 +
// permlane32_swap ((w0,w2)=swap(a0,a2), (w1,w3)=swap(a1,a3)) -- NO P LDS trip.
// PV: ctx = mfma(A=P[q][kv], B=Vt[d][kv]) accumulated in 4x f32x16.
// K/V staged via global_load_lds with granule-XOR swizzle on the GLOBAL source.
__global__ __launch_bounds__(256) void attn_kernel(const u16* __restrict__ Q,
                                                   const u16* __restrict__ K,
                                                   const u16* __restrict__ Vt,
                                                   u16* __restrict__ Octx) {
  __shared__ __align__(16) u16 Ks[64 * 128];
  __shared__ __align__(16) u16 Vs[128 * 64];
  __shared__ float Ls[4][32];
  const int tid = threadIdx.x, wave = tid >> 6, lane = tid & 63;
  const int bid = blockIdx.x;
  const int qb = bid & 15, bh = bid >> 4, b = bh >> 4, h = bh & 15;
  const int q0 = qb << 7;
  const int l31 = lane & 31, hi = lane >> 5;
  const float Cs = 0.08838834764831845f * 1.4426950408889634f;  // 1/sqrt(128)*log2(e)

  const u16* Qp = Q + ((size_t)(b * LQ_ + q0 + wave * 32 + l31)) * E_ + h * DH_;
  const u16* Kp = K + ((size_t)(b * LKV_)) * E_ + h * DH_;
  const u16* Vp = Vt + (size_t)bh * DH_ * LKV_;

  // Q B-frags: col=q=l31, k=dh=c*16+hi*8+j; prescaled by Cs.
  bf16x8 qf[8];
#pragma unroll
  for (int c = 0; c < 8; ++c) {
    bf16x8 raw = *(const bf16x8*)&Qp[c * 16 + hi * 8];
#pragma unroll
    for (int j = 0; j < 8; ++j) qf[c][j] = (__bf16)((float)raw[j] * Cs);
  }

  f32x16 o[4];
#pragma unroll
  for (int d = 0; d < 4; ++d)
#pragma unroll
    for (int r = 0; r < 16; ++r) o[d][r] = 0.f;
  float lsum = 0.f;

  const int kl_row = lane >> 4, kl_g = lane & 15;  // K stage: 4 rows of 256B
  const int vl_row = lane >> 3, vl_g = lane & 7;   // V stage: 8 rows of 128B

  for (int kv0 = 0; kv0 < LKV_; kv0 += 64) {
#pragma unroll
    for (int j = 0; j < 4; ++j) {
      int cc = wave * 4 + j;
      int krow = cc * 4 + kl_row;
      GLDS(Kp + (size_t)(kv0 + krow) * E_ + ((kl_g ^ (krow & 7)) << 3), &Ks[cc * 512]);
      int vrow = cc * 8 + vl_row;
      GLDS(Vp + (size_t)vrow * LKV_ + kv0 + ((vl_g ^ (vrow & 7)) << 3), &Vs[cc * 512]);
    }
    __syncthreads();

    // S^T[kv][q]: A = K rows (kv = n*32 + l31, k = dh), B = Q.
    f32x16 st[2];
#pragma unroll
    for (int n = 0; n < 2; ++n)
#pragma unroll
      for (int r = 0; r < 16; ++r) st[n][r] = 0.f;
#pragma unroll
    for (int c = 0; c < 8; ++c) {
#pragma unroll
      for (int n = 0; n < 2; ++n) {
        int row = n * 32 + l31;
        bf16x8 kf = *(const bf16x8*)&Ks[row * 128 + (((c * 2 + hi) ^ (row & 7)) << 3)];
        st[n] = __builtin_amdgcn_mfma_f32_32x32x16_bf16(kf, qf[c], st[n], 0, 0, 0);
      }
    }

    // P = exp2(S'), pack PV A-frags in-register.
    unsigned AF[4][4];
#pragma unroll
    for (int n = 0; n < 2; ++n) {
      float pv[16];
#pragma unroll
      for (int r = 0; r < 16; ++r) {
        pv[r] = exp2f(st[n][r]);
        lsum += pv[r];
      }
      unsigned a0 = cvtpk_bf16(pv[0], pv[1]),   a1 = cvtpk_bf16(pv[2], pv[3]);
      unsigned a2 = cvtpk_bf16(pv[4], pv[5]),   a3 = cvtpk_bf16(pv[6], pv[7]);
      unsigned b0 = cvtpk_bf16(pv[8], pv[9]),   b1 = cvtpk_bf16(pv[10], pv[11]);
      unsigned b2 = cvtpk_bf16(pv[12], pv[13]), b3 = cvtpk_bf16(pv[14], pv[15]);
      i32x2 r02 = __builtin_amdgcn_permlane32_swap((int)a0, (int)a2, false, false);
      i32x2 r13 = __builtin_amdgcn_permlane32_swap((int)a1, (int)a3, false, false);
      AF[n * 2][0] = (unsigned)r02[0]; AF[n * 2][1] = (unsigned)r13[0];
      AF[n * 2][2] = (unsigned)r02[1]; AF[n * 2][3] = (unsigned)r13[1];
      i32x2 s02 = __builtin_amdgcn_permlane32_swap((int)b0, (int)b2, false, false);
      i32x2 s13 = __builtin_amdgcn_permlane32_swap((int)b1, (int)b3, false, false);
      AF[n * 2 + 1][0] = (unsigned)s02[0]; AF[n * 2 + 1][1] = (unsigned)s13[0];
      AF[n * 2 + 1][2] = (unsigned)s02[1]; AF[n * 2 + 1][3] = (unsigned)s13[1];
    }

    // PV: A = P[q][kv-step], B = Vt[d][kv].
#pragma unroll
    for (int s = 0; s < 4; ++s) {
      union { unsigned u[4]; bf16x8 v; } pk;
      pk.u[0] = AF[s][0]; pk.u[1] = AF[s][1]; pk.u[2] = AF[s][2]; pk.u[3] = AF[s][3];
      bf16x8 pa = pk.v;
#pragma unroll
      for (int db = 0; db < 4; ++db) {
        int d = db * 32 + l31;
        bf16x8 vf = *(const bf16x8*)&Vs[d * 64 + (((s * 2 + hi) ^ (d & 7)) << 3)];
        o[db] = __builtin_amdgcn_mfma_f32_32x32x16_bf16(pa, vf, o[db], 0, 0, 0);
      }
    }
    __syncthreads();
  }

  // l: lane+partner hold complementary kv halves of the same q
  lsum += __shfl_xor(lsum, 32);
  if (lane < 32) Ls[wave][lane] = 1.0f / lsum;
  __syncthreads();

#pragma unroll
  for (int r = 0; r < 16; ++r) {
    int crow = (r & 3) + 8 * (r >> 2) + 4 * hi;
    float li = Ls[wave][crow];
    size_t rb = ((size_t)(b * LQ_ + q0 + wave * 32 + crow)) * E_ + h * DH_ + l31;
#pragma unroll
    for (int db = 0; db < 4; ++db)
      Octx[rb + db * 32] = f2bf(o[db][r] * li);
  }
}

// ------------------------------------------------- RMSNorm (Gemma) + residual
__global__ __launch_bounds__(256) void rms_res(const float* __restrict__ x,
                                               const float* __restrict__ w,
                                               const float* __restrict__ qres,
                                               float* __restrict__ out) {
  int row = blockIdx.x, tid = threadIdx.x;
  const float4* xr = (const float4*)(x + (size_t)row * E_);
  const float4* qr = (const float4*)(qres + (size_t)row * E_);
  const float4* wr4 = (const float4*)w;
  float4 v0 = xr[tid * 2], v1 = xr[tid * 2 + 1];
  float ss = v0.x * v0.x + v0.y * v0.y + v0.z * v0.z + v0.w * v0.w +
             v1.x * v1.x + v1.y * v1.y + v1.z * v1.z + v1.w * v1.w;
  ss += __shfl_xor(ss, 1);  ss += __shfl_xor(ss, 2);
  ss += __shfl_xor(ss, 4);  ss += __shfl_xor(ss, 8);
  ss += __shfl_xor(ss, 16); ss += __shfl_xor(ss, 32);
  __shared__ float ls[4];
  if ((tid & 63) == 0) ls[tid >> 6] = ss;
  __syncthreads();
  float total = ls[0] + ls[1] + ls[2] + ls[3];
  float rs = rsqrtf(total * (1.0f / (float)E_) + 1e-6f);
  float4 q0 = qr[tid * 2], q1 = qr[tid * 2 + 1];
  float4 w0 = wr4[tid * 2], w1 = wr4[tid * 2 + 1];
  float4 o0, o1;
  o0.x = v0.x * rs * (1.f + w0.x) + q0.x;
  o0.y = v0.y * rs * (1.f + w0.y) + q0.y;
  o0.z = v0.z * rs * (1.f + w0.z) + q0.z;
  o0.w = v0.w * rs * (1.f + w0.w) + q0.w;
  o1.x = v1.x * rs * (1.f + w1.x) + q1.x;
  o1.y = v1.y * rs * (1.f + w1.y) + q1.y;
  o1.z = v1.z * rs * (1.f + w1.z) + q1.z;
  o1.w = v1.w * rs * (1.f + w1.w) + q1.w;
  float4* op = (float4*)(out + (size_t)row * E_);
  op[tid * 2] = o0;
  op[tid * 2 + 1] = o1;
}

// ------------------------------------------------- launcher
extern "C" void kernel_launch(void* const* d_in, const int* in_sizes, int n_in,
                              void* d_out, int out_size, void* d_ws, size_t ws_size,
                              hipStream_t stream) {
  const float* query = (const float*)d_in[0];
  const float* aug   = (const float*)d_in[1];
  // d_in[2] = aug_mask: unused by the reference forward
  const float* projw = (const float*)d_in[3];
  const float* projb = (const float*)d_in[4];
  const float* ipw   = (const float*)d_in[5];
  const float* ipb   = (const float*)d_in[6];
  const float* opw   = (const float*)d_in[7];
  const float* opb   = (const float*)d_in[8];
  const float* rmsw  = (const float*)d_in[9];

  char* ws = (char*)d_ws;
  size_t off = 0;
  auto alloc = [&](size_t bytes) {
    void* p = ws + off;
    off += (bytes + 1023) & ~(size_t)1023;
    return p;
  };
  // Region 0 (dead by out-proj time): reused as attn_out f32
  u16* query_bf = (u16*)alloc((size_t)B_ * LQ_ * E_ * 2);        // 33.6MB
  u16* aug_bf   = (u16*)alloc((size_t)B_ * LKV_ * AUG_ * 2);     // 16.8MB
  u16* projw_bf = (u16*)alloc((size_t)E_ * AUG_ * 2);            //  4.2MB
  u16* w_bf     = (u16*)alloc((size_t)3 * E_ * E_ * 2);          // 25.2MB
  u16* outw_bf  = (u16*)alloc((size_t)E_ * E_ * 2);              //  8.4MB
  u16* kv_bf    = (u16*)alloc((size_t)B_ * LKV_ * E_ * 2);       // 33.6MB (later: vt)
  u16* q_bf     = (u16*)alloc((size_t)B_ * LQ_ * E_ * 2);
  u16* k_bf     = (u16*)alloc((size_t)B_ * LKV_ * E_ * 2);
  u16* v_bf     = (u16*)alloc((size_t)B_ * LKV_ * E_ * 2);
  u16* ctx_bf   = (u16*)alloc((size_t)B_ * LQ_ * E_ * 2);
  float* attn_out = (float*)query_bf;  // alias: region 0 all dead by then
  u16* vt_bf = kv_bf;                  // alias: kv dead after v GEMM
  (void)in_sizes; (void)n_in; (void)ws_size;

  const int M = B_ * LQ_;  // 8192

  cast_bf16<<<1024, 256, 0, stream>>>(query, query_bf, (int)((size_t)M * E_ / 8));
  cast_bf16<<<1024, 256, 0, stream>>>(aug, aug_bf, (int)((size_t)M * AUG_ / 8));
  cast_bf16<<<512, 256, 0, stream>>>(projw, projw_bf, (int)((size_t)E_ * AUG_ / 8));
  cast_bf16<<<1024, 256, 0, stream>>>(ipw, w_bf, (int)((size_t)3 * E_ * E_ / 8));
  cast_bf16<<<512, 256, 0, stream>>>(opw, outw_bf, (int)((size_t)E_ * E_ / 8));

  // kv = aug @ proj_w^T + proj_b
  gemm_bt2<0><<<dim3(E_ / 256, M / 256), 512, 0, stream>>>(aug_bf, projw_bf, projb, kv_bf, E_, AUG_);
  // q = query @ wq^T + bq
  gemm_bt2<0><<<dim3(E_ / 256, M / 256), 512, 0, stream>>>(query_bf, w_bf, ipb, q_bf, E_, E_);
  // k = kv @ wk^T + bk
  gemm_bt2<0><<<dim3(E_ / 256, M / 256), 512, 0, stream>>>(kv_bf, w_bf + (size_t)E_ * E_, ipb + E_, k_bf, E_, E_);
  // v = kv @ wv^T + bv
  gemm_bt2<0><<<dim3(E_ / 256, M / 256), 512, 0, stream>>>(kv_bf, w_bf + (size_t)2 * E_ * E_, ipb + 2 * E_, v_bf, E_, E_);
  // vt[b,h,d,kv] = v[b,kv,h,d]
  transpose_v<<<dim3(LKV_ / 64, DH_ / 64, B_ * H_), 256, 0, stream>>>(v_bf, vt_bf);
  // attention -> ctx  (QBLK=128 per block)
  attn_kernel<<<B_ * H_ * (LQ_ / 128), 256, 0, stream>>>(q_bf, k_bf, vt_bf, ctx_bf);
  // attn_out = ctx @ out_proj^T + b (f32)
  gemm_bt2<1><<<dim3(E_ / 256, M / 256), 512, 0, stream>>>(ctx_bf, outw_bf, opb, attn_out, E_, E_);
  // out = RMSNorm(attn_out)*(1+w) + query
  rms_res<<<M, 256, 0, stream>>>(attn_out, rmsw, query, (float*)d_out);
}

// Round 8
// 554.729 us; speedup vs baseline: 1.1410x; 1.1410x over previous
//
#include <hip/hip_runtime.h>
#include <hip/hip_bf16.h>
#include <stdint.h>

// Problem constants
#define B_   4
#define LQ_  2048
#define LKV_ 2048
#define E_   2048
#define AUG_ 1024
#define H_   16
#define DH_  128

typedef unsigned short u16;
typedef __bf16 bf16x8 __attribute__((ext_vector_type(8)));
typedef float f32x4 __attribute__((ext_vector_type(4)));
typedef float f32x16 __attribute__((ext_vector_type(16)));
typedef int i32x2 __attribute__((ext_vector_type(2)));

__device__ __forceinline__ u16 f2bf(float f) {
  union { float f; unsigned u; } v; v.f = f;
  unsigned r = v.u + 0x7fffu + ((v.u >> 16) & 1u);
  return (u16)(r >> 16);
}
__device__ __forceinline__ unsigned pk2(float a, float b) {
  return (unsigned)f2bf(a) | ((unsigned)f2bf(b) << 16);
}
// v_cvt_pk_bf16_f32: lo -> bits[15:0], hi -> bits[31:16] (no builtin on gfx950)
__device__ __forceinline__ unsigned cvtpk_bf16(float lo, float hi) {
  unsigned r;
  asm("v_cvt_pk_bf16_f32 %0, %1, %2" : "=v"(r) : "v"(lo), "v"(hi));
  return r;
}

// async global->LDS, 16B per lane. LDS dest must be wave-uniform; HW adds lane*16.
#define GLDS(gsrc, ldst)                                                        \
  __builtin_amdgcn_global_load_lds(                                             \
      (__attribute__((address_space(1))) void*)(uintptr_t)(gsrc),               \
      (__attribute__((address_space(3))) void*)(unsigned)(uintptr_t)(ldst),     \
      16, 0, 0)

// raw workgroup barrier with compiler memory-motion fences (NO vmcnt drain)
#define BARRIER()                                   \
  do {                                              \
    asm volatile("" ::: "memory");                  \
    __builtin_amdgcn_s_barrier();                   \
    asm volatile("" ::: "memory");                  \
  } while (0)

// ---------------------------------------------------------------- cast f32->bf16
__global__ __launch_bounds__(256) void cast_bf16(const float* __restrict__ in,
                                                 u16* __restrict__ out, int n8) {
  int stride = gridDim.x * blockDim.x;
  for (int i = blockIdx.x * blockDim.x + threadIdx.x; i < n8; i += stride) {
    const float4* p = (const float4*)in + (size_t)i * 2;
    float4 a = p[0], b = p[1];
    uint4 o;
    o.x = pk2(a.x, a.y); o.y = pk2(a.z, a.w);
    o.z = pk2(b.x, b.y); o.w = pk2(b.z, b.w);
    ((uint4*)out)[i] = o;
  }
}

// ------------------------------------------------- GEMM: C[M,N] = A[M,K]*W[N,K]^T + bias
// 256x256 tile, 8 waves (2M x 4N), BK=32, ring-of-3 K-tile LDS pipeline (96 KiB).
template <int OUTF32>
__global__ __launch_bounds__(512, 2) void gemm_bt2(const u16* __restrict__ A,
                                                   const u16* __restrict__ W,
                                                   const float* __restrict__ bias,
                                                   void* __restrict__ Cp,
                                                   int N, int K) {
  __shared__ __align__(16) u16 As[3][256 * 32];
  __shared__ __align__(16) u16 Bs[3][256 * 32];
  const int tid = threadIdx.x;
  const int wave = tid >> 6, lane = tid & 63;
  const int wr = wave >> 2, wc = wave & 3;          // 2 x 4 wave grid
  const int g = lane >> 4, r16 = lane & 15;
  const int m0 = blockIdx.y << 8, n0 = blockIdx.x << 8;

  size_t gA[2], gB[2];
  int ldst[2];
#pragma unroll
  for (int i = 0; i < 2; ++i) {
    int c = tid + i * 512;
    int s = c >> 6, w = c & 63;
    int wp = w ^ (((w >> 5) & 1) << 1);
    int grow = s * 16 + (wp >> 2);
    int gcol = (wp & 3) * 8;
    gA[i] = (size_t)(m0 + grow) * K + gcol;
    gB[i] = (size_t)(n0 + grow) * K + gcol;
    ldst[i] = c * 8;  // u16 elements (16B chunks)
  }
  const int aoff = r16 * 32 + ((g * 8) ^ ((r16 & 8) ? 16 : 0));

  f32x4 acc[8][4];
#pragma unroll
  for (int m = 0; m < 8; ++m)
#pragma unroll
    for (int n = 0; n < 4; ++n) acc[m][n] = (f32x4){0.f, 0.f, 0.f, 0.f};

  const int NT = K >> 5;
#pragma unroll
  for (int i = 0; i < 2; ++i) GLDS(A + gA[i], &As[0][ldst[i]]);
#pragma unroll
  for (int i = 0; i < 2; ++i) GLDS(W + gB[i], &Bs[0][ldst[i]]);
#pragma unroll
  for (int i = 0; i < 2; ++i) GLDS(A + gA[i] + 32, &As[1][ldst[i]]);
#pragma unroll
  for (int i = 0; i < 2; ++i) GLDS(W + gB[i] + 32, &Bs[1][ldst[i]]);

  int cur = 0;
  for (int t = 0; t < NT; ++t) {
    if (t + 1 < NT)
      asm volatile("s_waitcnt vmcnt(4)" ::: "memory");
    else
      asm volatile("s_waitcnt vmcnt(0)" ::: "memory");
    BARRIER();

    const u16* as = As[cur];
    const u16* bs = Bs[cur];
    int nxt = cur + 2; if (nxt >= 3) nxt -= 3;

    bf16x8 bfr[4], af[4];
#pragma unroll
    for (int n = 0; n < 4; ++n)
      bfr[n] = *(const bf16x8*)&bs[wc * 2048 + n * 512 + aoff];
#pragma unroll
    for (int m = 0; m < 4; ++m)
      af[m] = *(const bf16x8*)&as[wr * 4096 + m * 512 + aoff];
    if (t + 2 < NT) {
      size_t k0 = (size_t)(t + 2) * 32;
#pragma unroll
      for (int i = 0; i < 2; ++i) GLDS(A + gA[i] + k0, &As[nxt][ldst[i]]);
    }
    BARRIER();
    __builtin_amdgcn_s_setprio(1);
#pragma unroll
    for (int m = 0; m < 4; ++m)
#pragma unroll
      for (int n = 0; n < 4; ++n)
        acc[m][n] = __builtin_amdgcn_mfma_f32_16x16x32_bf16(af[m], bfr[n], acc[m][n], 0, 0, 0);
    __builtin_amdgcn_s_setprio(0);

    bf16x8 af2[4];
#pragma unroll
    for (int m = 0; m < 4; ++m)
      af2[m] = *(const bf16x8*)&as[wr * 4096 + (m + 4) * 512 + aoff];
    if (t + 2 < NT) {
      size_t k0 = (size_t)(t + 2) * 32;
#pragma unroll
      for (int i = 0; i < 2; ++i) GLDS(W + gB[i] + k0, &Bs[nxt][ldst[i]]);
    }
    BARRIER();
    __builtin_amdgcn_s_setprio(1);
#pragma unroll
    for (int m = 0; m < 4; ++m)
#pragma unroll
      for (int n = 0; n < 4; ++n)
        acc[m + 4][n] = __builtin_amdgcn_mfma_f32_16x16x32_bf16(af2[m], bfr[n], acc[m + 4][n], 0, 0, 0);
    __builtin_amdgcn_s_setprio(0);

    cur = cur + 1; if (cur >= 3) cur -= 3;
  }

  float bv[4];
#pragma unroll
  for (int n = 0; n < 4; ++n)
    bv[n] = bias ? bias[n0 + wc * 64 + n * 16 + r16] : 0.f;
#pragma unroll
  for (int m = 0; m < 8; ++m) {
    int row = m0 + wr * 128 + m * 16 + g * 4;
#pragma unroll
    for (int n = 0; n < 4; ++n) {
      int col = n0 + wc * 64 + n * 16 + r16;
#pragma unroll
      for (int r = 0; r < 4; ++r) {
        float v = acc[m][n][r] + bv[n];
        if (OUTF32)
          ((float*)Cp)[(size_t)(row + r) * N + col] = v;
        else
          ((u16*)Cp)[(size_t)(row + r) * N + col] = f2bf(v);
      }
    }
  }
}

// ------------------------------------------------- V transpose: [B,LKV,H,DH] -> [B,H,DH,LKV]
__global__ __launch_bounds__(256) void transpose_v(const u16* __restrict__ v,
                                                   u16* __restrict__ vt) {
  __shared__ __align__(16) u16 t[64][72];
  int tid = threadIdx.x;
  int bh = blockIdx.z, b = bh >> 4, h = bh & 15;
  int kv0 = blockIdx.x << 6, d0 = blockIdx.y << 6;
  int gr = tid & 7, rw = tid >> 3;  // rw 0..31
#pragma unroll
  for (int p = 0; p < 2; ++p) {
    int row = rw + p * 32;  // kv-local
    uint4 x = *(const uint4*)&v[((size_t)(b * LKV_) + kv0 + row) * E_ + h * DH_ + d0 + gr * 8];
    *(uint4*)&t[row][gr * 8] = x;
  }
  __syncthreads();
#pragma unroll
  for (int p = 0; p < 2; ++p) {
    int d = rw + p * 32;  // d-local
    u16 tmp[8];
#pragma unroll
    for (int j = 0; j < 8; ++j) tmp[j] = t[gr * 8 + j][d];
    uint4 o;
    o.x = (unsigned)tmp[0] | ((unsigned)tmp[1] << 16);
    o.y = (unsigned)tmp[2] | ((unsigned)tmp[3] << 16);
    o.z = (unsigned)tmp[4] | ((unsigned)tmp[5] << 16);
    o.w = (unsigned)tmp[6] | ((unsigned)tmp[7] << 16);
    *(uint4*)&vt[(((size_t)(b * H_ + h)) * DH_ + d0 + d) * LKV_ + kv0 + gr * 8] = o;
  }
}

// ------------------------------------------------- flash attention (m214-style)
// Block: 256 thr (4 waves), QBLK=128 (32 q-rows/wave), KVBLK=64, 32x32x16 MFMA.
// Swapped QK^T: S^T = mfma(A=K, B=Q) -> lane owns q = lane&31; kv spread over
// 16 regs x hi-half: kv = (r&3)+8*(r>>2)+4*hi (+n*32).
// Fixed-shift softmax in-register; P -> bf16 PV A-frags via v_cvt_pk_bf16_f32 +
// permlane32_swap -- NO P LDS trip.
// K/V DOUBLE-BUFFERED in LDS (T3-lite 2-phase pipeline): issue tile t+1's
// global_load_lds first, s_waitcnt vmcnt(8) (own tile-t loads done; never
// drain to 0 mid-loop), raw s_barrier, compute tile t, barrier.
__global__ __launch_bounds__(256) void attn_kernel(const u16* __restrict__ Q,
                                                   const u16* __restrict__ K,
                                                   const u16* __restrict__ Vt,
                                                   u16* __restrict__ Octx) {
  __shared__ __align__(16) u16 Ks[2][64 * 128];
  __shared__ __align__(16) u16 Vs[2][128 * 64];
  __shared__ float Ls[4][32];
  const int tid = threadIdx.x, wave = tid >> 6, lane = tid & 63;
  const int bid = blockIdx.x;
  const int qb = bid & 15, bh = bid >> 4, b = bh >> 4, h = bh & 15;
  const int q0 = qb << 7;
  const int l31 = lane & 31, hi = lane >> 5;
  const float Cs = 0.08838834764831845f * 1.4426950408889634f;  // 1/sqrt(128)*log2(e)

  const u16* Qp = Q + ((size_t)(b * LQ_ + q0 + wave * 32 + l31)) * E_ + h * DH_;
  const u16* Kp = K + ((size_t)(b * LKV_)) * E_ + h * DH_;
  const u16* Vp = Vt + (size_t)bh * DH_ * LKV_;

  const int kl_row = lane >> 4, kl_g = lane & 15;  // K stage: 4 rows of 256B
  const int vl_row = lane >> 3, vl_g = lane & 7;   // V stage: 8 rows of 128B

  // Q B-frags: col=q=l31, k=dh=c*16+hi*8+j; prescaled by Cs.
  bf16x8 qf[8];
#pragma unroll
  for (int c = 0; c < 8; ++c) {
    bf16x8 raw = *(const bf16x8*)&Qp[c * 16 + hi * 8];
#pragma unroll
    for (int j = 0; j < 8; ++j) qf[c][j] = (__bf16)((float)raw[j] * Cs);
  }

  f32x16 o[4];
#pragma unroll
  for (int d = 0; d < 4; ++d)
#pragma unroll
    for (int r = 0; r < 16; ++r) o[d][r] = 0.f;
  float lsum = 0.f;

  // stage kv-tile (8 global_load_lds) into buffer `buf`
  auto STAGE = [&](int kv0, int buf) {
#pragma unroll
    for (int j = 0; j < 4; ++j) {
      int cc = wave * 4 + j;
      int krow = cc * 4 + kl_row;
      GLDS(Kp + (size_t)(kv0 + krow) * E_ + ((kl_g ^ (krow & 7)) << 3), &Ks[buf][cc * 512]);
      int vrow = cc * 8 + vl_row;
      GLDS(Vp + (size_t)vrow * LKV_ + kv0 + ((vl_g ^ (vrow & 7)) << 3), &Vs[buf][cc * 512]);
    }
  };

  const int NT = LKV_ / 64;
  STAGE(0, 0);

  for (int t = 0; t < NT; ++t) {
    const int cur = t & 1;
    if (t + 1 < NT) {
      STAGE((t + 1) * 64, cur ^ 1);  // buf cur^1 released by end-barrier of t-1
      asm volatile("s_waitcnt vmcnt(8)" ::: "memory");  // own tile-t loads done
    } else {
      asm volatile("s_waitcnt vmcnt(0)" ::: "memory");
    }
    BARRIER();  // all waves' tile-t loads visible

    const u16* ks = Ks[cur];
    const u16* vs = Vs[cur];

    // S^T[kv][q]: A = K rows (kv = n*32 + l31, k = dh), B = Q.
    f32x16 st[2];
#pragma unroll
    for (int n = 0; n < 2; ++n)
#pragma unroll
      for (int r = 0; r < 16; ++r) st[n][r] = 0.f;
#pragma unroll
    for (int c = 0; c < 8; ++c) {
#pragma unroll
      for (int n = 0; n < 2; ++n) {
        int row = n * 32 + l31;
        bf16x8 kf = *(const bf16x8*)&ks[row * 128 + (((c * 2 + hi) ^ (row & 7)) << 3)];
        st[n] = __builtin_amdgcn_mfma_f32_32x32x16_bf16(kf, qf[c], st[n], 0, 0, 0);
      }
    }

    // P = exp2(S'), pack PV A-frags in-register.
    unsigned AF[4][4];
#pragma unroll
    for (int n = 0; n < 2; ++n) {
      float pv[16];
#pragma unroll
      for (int r = 0; r < 16; ++r) {
        pv[r] = exp2f(st[n][r]);
        lsum += pv[r];
      }
      unsigned a0 = cvtpk_bf16(pv[0], pv[1]),   a1 = cvtpk_bf16(pv[2], pv[3]);
      unsigned a2 = cvtpk_bf16(pv[4], pv[5]),   a3 = cvtpk_bf16(pv[6], pv[7]);
      unsigned b0 = cvtpk_bf16(pv[8], pv[9]),   b1 = cvtpk_bf16(pv[10], pv[11]);
      unsigned b2 = cvtpk_bf16(pv[12], pv[13]), b3 = cvtpk_bf16(pv[14], pv[15]);
      i32x2 r02 = __builtin_amdgcn_permlane32_swap((int)a0, (int)a2, false, false);
      i32x2 r13 = __builtin_amdgcn_permlane32_swap((int)a1, (int)a3, false, false);
      AF[n * 2][0] = (unsigned)r02[0]; AF[n * 2][1] = (unsigned)r13[0];
      AF[n * 2][2] = (unsigned)r02[1]; AF[n * 2][3] = (unsigned)r13[1];
      i32x2 s02 = __builtin_amdgcn_permlane32_swap((int)b0, (int)b2, false, false);
      i32x2 s13 = __builtin_amdgcn_permlane32_swap((int)b1, (int)b3, false, false);
      AF[n * 2 + 1][0] = (unsigned)s02[0]; AF[n * 2 + 1][1] = (unsigned)s13[0];
      AF[n * 2 + 1][2] = (unsigned)s02[1]; AF[n * 2 + 1][3] = (unsigned)s13[1];
    }

    // PV: A = P[q][kv-step], B = Vt[d][kv].
#pragma unroll
    for (int s = 0; s < 4; ++s) {
      union { unsigned u[4]; bf16x8 v; } pk;
      pk.u[0] = AF[s][0]; pk.u[1] = AF[s][1]; pk.u[2] = AF[s][2]; pk.u[3] = AF[s][3];
      bf16x8 pa = pk.v;
#pragma unroll
      for (int db = 0; db < 4; ++db) {
        int d = db * 32 + l31;
        bf16x8 vf = *(const bf16x8*)&vs[d * 64 + (((s * 2 + hi) ^ (d & 7)) << 3)];
        o[db] = __builtin_amdgcn_mfma_f32_32x32x16_bf16(pa, vf, o[db], 0, 0, 0);
      }
    }
    BARRIER();  // all waves done reading buf cur -> free for staging at t+1
  }

  // l: lane+partner hold complementary kv halves of the same q
  lsum += __shfl_xor(lsum, 32);
  if (lane < 32) Ls[wave][lane] = 1.0f / lsum;
  __syncthreads();

#pragma unroll
  for (int r = 0; r < 16; ++r) {
    int crow = (r & 3) + 8 * (r >> 2) + 4 * hi;
    float li = Ls[wave][crow];
    size_t rb = ((size_t)(b * LQ_ + q0 + wave * 32 + crow)) * E_ + h * DH_ + l31;
#pragma unroll
    for (int db = 0; db < 4; ++db)
      Octx[rb + db * 32] = f2bf(o[db][r] * li);
  }
}

// ------------------------------------------------- RMSNorm (Gemma) + residual
__global__ __launch_bounds__(256) void rms_res(const float* __restrict__ x,
                                               const float* __restrict__ w,
                                               const float* __restrict__ qres,
                                               float* __restrict__ out) {
  int row = blockIdx.x, tid = threadIdx.x;
  const float4* xr = (const float4*)(x + (size_t)row * E_);
  const float4* qr = (const float4*)(qres + (size_t)row * E_);
  const float4* wr4 = (const float4*)w;
  float4 v0 = xr[tid * 2], v1 = xr[tid * 2 + 1];
  float ss = v0.x * v0.x + v0.y * v0.y + v0.z * v0.z + v0.w * v0.w +
             v1.x * v1.x + v1.y * v1.y + v1.z * v1.z + v1.w * v1.w;
  ss += __shfl_xor(ss, 1);  ss += __shfl_xor(ss, 2);
  ss += __shfl_xor(ss, 4);  ss += __shfl_xor(ss, 8);
  ss += __shfl_xor(ss, 16); ss += __shfl_xor(ss, 32);
  __shared__ float ls[4];
  if ((tid & 63) == 0) ls[tid >> 6] = ss;
  __syncthreads();
  float total = ls[0] + ls[1] + ls[2] + ls[3];
  float rs = rsqrtf(total * (1.0f / (float)E_) + 1e-6f);
  float4 q0 = qr[tid * 2], q1 = qr[tid * 2 + 1];
  float4 w0 = wr4[tid * 2], w1 = wr4[tid * 2 + 1];
  float4 o0, o1;
  o0.x = v0.x * rs * (1.f + w0.x) + q0.x;
  o0.y = v0.y * rs * (1.f + w0.y) + q0.y;
  o0.z = v0.z * rs * (1.f + w0.z) + q0.z;
  o0.w = v0.w * rs * (1.f + w0.w) + q0.w;
  o1.x = v1.x * rs * (1.f + w1.x) + q1.x;
  o1.y = v1.y * rs * (1.f + w1.y) + q1.y;
  o1.z = v1.z * rs * (1.f + w1.z) + q1.z;
  o1.w = v1.w * rs * (1.f + w1.w) + q1.w;
  float4* op = (float4*)(out + (size_t)row * E_);
  op[tid * 2] = o0;
  op[tid * 2 + 1] = o1;
}

// ------------------------------------------------- launcher
extern "C" void kernel_launch(void* const* d_in, const int* in_sizes, int n_in,
                              void* d_out, int out_size, void* d_ws, size_t ws_size,
                              hipStream_t stream) {
  const float* query = (const float*)d_in[0];
  const float* aug   = (const float*)d_in[1];
  // d_in[2] = aug_mask: unused by the reference forward
  const float* projw = (const float*)d_in[3];
  const float* projb = (const float*)d_in[4];
  const float* ipw   = (const float*)d_in[5];
  const float* ipb   = (const float*)d_in[6];
  const float* opw   = (const float*)d_in[7];
  const float* opb   = (const float*)d_in[8];
  const float* rmsw  = (const float*)d_in[9];

  char* ws = (char*)d_ws;
  size_t off = 0;
  auto alloc = [&](size_t bytes) {
    void* p = ws + off;
    off += (bytes + 1023) & ~(size_t)1023;
    return p;
  };
  // Region 0 (dead by out-proj time): reused as attn_out f32
  u16* query_bf = (u16*)alloc((size_t)B_ * LQ_ * E_ * 2);        // 33.6MB
  u16* aug_bf   = (u16*)alloc((size_t)B_ * LKV_ * AUG_ * 2);     // 16.8MB
  u16* projw_bf = (u16*)alloc((size_t)E_ * AUG_ * 2);            //  4.2MB
  u16* w_bf     = (u16*)alloc((size_t)3 * E_ * E_ * 2);          // 25.2MB
  u16* outw_bf  = (u16*)alloc((size_t)E_ * E_ * 2);              //  8.4MB
  u16* kv_bf    = (u16*)alloc((size_t)B_ * LKV_ * E_ * 2);       // 33.6MB (later: vt)
  u16* q_bf     = (u16*)alloc((size_t)B_ * LQ_ * E_ * 2);
  u16* k_bf     = (u16*)alloc((size_t)B_ * LKV_ * E_ * 2);
  u16* v_bf     = (u16*)alloc((size_t)B_ * LKV_ * E_ * 2);
  u16* ctx_bf   = (u16*)alloc((size_t)B_ * LQ_ * E_ * 2);
  float* attn_out = (float*)query_bf;  // alias: region 0 all dead by then
  u16* vt_bf = kv_bf;                  // alias: kv dead after v GEMM
  (void)in_sizes; (void)n_in; (void)ws_size;

  const int M = B_ * LQ_;  // 8192

  cast_bf16<<<1024, 256, 0, stream>>>(query, query_bf, (int)((size_t)M * E_ / 8));
  cast_bf16<<<1024, 256, 0, stream>>>(aug, aug_bf, (int)((size_t)M * AUG_ / 8));
  cast_bf16<<<512, 256, 0, stream>>>(projw, projw_bf, (int)((size_t)E_ * AUG_ / 8));
  cast_bf16<<<1024, 256, 0, stream>>>(ipw, w_bf, (int)((size_t)3 * E_ * E_ / 8));
  cast_bf16<<<512, 256, 0, stream>>>(opw, outw_bf, (int)((size_t)E_ * E_ / 8));

  // kv = aug @ proj_w^T + proj_b
  gemm_bt2<0><<<dim3(E_ / 256, M / 256), 512, 0, stream>>>(aug_bf, projw_bf, projb, kv_bf, E_, AUG_);
  // q = query @ wq^T + bq
  gemm_bt2<0><<<dim3(E_ / 256, M / 256), 512, 0, stream>>>(query_bf, w_bf, ipb, q_bf, E_, E_);
  // k = kv @ wk^T + bk
  gemm_bt2<0><<<dim3(E_ / 256, M / 256), 512, 0, stream>>>(kv_bf, w_bf + (size_t)E_ * E_, ipb + E_, k_bf, E_, E_);
  // v = kv @ wv^T + bv
  gemm_bt2<0><<<dim3(E_ / 256, M / 256), 512, 0, stream>>>(kv_bf, w_bf + (size_t)2 * E_ * E_, ipb + 2 * E_, v_bf, E_, E_);
  // vt[b,h,d,kv] = v[b,kv,h,d]
  transpose_v<<<dim3(LKV_ / 64, DH_ / 64, B_ * H_), 256, 0, stream>>>(v_bf, vt_bf);
  // attention -> ctx  (QBLK=128 per block)
  attn_kernel<<<B_ * H_ * (LQ_ / 128), 256, 0, stream>>>(q_bf, k_bf, vt_bf, ctx_bf);
  // attn_out = ctx @ out_proj^T + b (f32)
  gemm_bt2<1><<<dim3(E_ / 256, M / 256), 512, 0, stream>>>(ctx_bf, outw_bf, opb, attn_out, E_, E_);
  // out = RMSNorm(attn_out)*(1+w) + query
  rms_res<<<M, 256, 0, stream>>>(attn_out, rmsw, query, (float*)d_out);
}